// Round 12
// baseline (418.293 us; speedup 1.0000x reference)
//
#include <hip/hip_runtime.h>
#include <hip/hip_bf16.h>

typedef _Float16 v8h __attribute__((ext_vector_type(8)));
typedef _Float16 v4h __attribute__((ext_vector_type(4)));
typedef _Float16 v2h __attribute__((ext_vector_type(2)));
typedef float    v4f __attribute__((ext_vector_type(4)));

#define NTOT  16384
#define NN    70
#define STEPS 5
#define GPB   3                      // graphs per batch
#define NBAT  2                      // independent batches per block
#define NB    (GPB*NBAT)             // 6 graphs per block
#define TPB   320                    // 5 waves = 5 node-tiles of 16
#define NBLK  ((NTOT + NB - 1)/NB)   // 2731
#define CATN  40                     // cat node stride (halves)
// CATG MUST cover 80 nodes (phantom nodes 70..79 are READ by MFMA phases and
// must return zero, not garbage) -- R11's 2808 caused OOB NaN. 3208 = 80*40+8;
// 1604 dw == 4 mod 32.
#define CATG  3208
#define CATB  (GPB*CATG)             // 9624 halves per batch
#define USTR  232                    // U col stride: 116 dw == 20 mod 32 (2-way max)
#define UCOLS 30
#define UBUF  (UCOLS*USTR)           // 6960 halves per buffer
#define UHALV (4*UBUF)               // 27840: [batch][parity] buffers
#define SMHALV (UHALV + NBAT*CATB)   // 47088 halves
#define SMBYTES (SMHALV*2)           // 94176 B dynamic LDS -> 1 block/CU

// epilogue weights (fp32, global scalar loads)
#define PWO1 0                       // 10 rows x 12: [Wo1[s][0..9], ann_coef, bo1[s]]
#define PWO2 120
#define PBO2 130
#define NWP  132

// fp16 fragment images (built by prep):
//  [0..1023]     P1 B-frags Wstack, 2 tiles:  nt*512 + lane*8 + j
//  [1024..2047]  P3 A-frags Wr | Wz:          mt*512 + lane*8 + j
//  [2048..2559]  P3 A-frag  Wh:               lane*8 + j
//  [2560..20479] adjacency A-frags:           2560 + (w*7+kt)*512 + lane*8 + j
#define OFR  1024
#define OFZ  1536
#define OFH  2048
#define OFA  2560
#define NWF  20480

__device__ __align__(16) float    g_w[NWP];
__device__ __align__(16) _Float16 g_wf[NWF];
__device__ int g_flag;

__device__ __forceinline__ float fast_sigmoid(float x) {
    return __builtin_amdgcn_rcpf(1.0f + __expf(-x));
}
__device__ __forceinline__ float fast_tanh(float x) {
    float ax = fabsf(x);
    float e  = __expf(-2.0f * ax);
    float t  = (1.0f - e) * __builtin_amdgcn_rcpf(1.0f + e);
    return copysignf(t, x);
}

// ---- prep: probe dtype; build epilogue weights + all fp16 fragment images ----
__global__ void prep_kernel(const void* annv, const void* Av,
    const void* winv, const void* binv, const void* wrv, const void* brv,
    const void* wzv, const void* bzv, const void* whv, const void* bhv,
    const void* wo1v, const void* bo1v, const void* wo2v, const void* bo2v)
{
    __shared__ int sflag;
    if (threadIdx.x == 0) {
        const unsigned short* u = (const unsigned short*)annv;
        int good = 0;
        for (int k = 0; k < 128; ++k) {
            unsigned short bb = u[k];
            int ex = (bb >> 7) & 0xFF;
            if (bb == 0 || (ex >= 101 && ex <= 131)) ++good;
        }
        sflag = (good >= 112) ? 1 : 0;
        g_flag = sflag;
    }
    __syncthreads();
    const int f = sflag;
    #define RD(p, i) (f ? (float)((const __hip_bfloat16*)(p))[i] : ((const float*)(p))[i])
    const int tid = threadIdx.x;
    for (int idx = tid; idx < 120; idx += blockDim.x) {
        const int s = idx / 12, c = idx - s*12;
        g_w[PWO1 + idx] = (c < 11) ? RD(wo1v, s*11 + c) : RD(bo1v, s);
    }
    for (int idx = tid; idx < 10; idx += blockDim.x) g_w[PWO2 + idx] = RD(wo2v, idx);
    if (tid == 0) { g_w[PBO2] = RD(bo2v, 0); g_w[PBO2+1] = 0.f; }
    for (int idx = tid; idx < NWF; idx += blockDim.x) {
        float val = 0.f;
        if (idx < OFR) {
            // P1 B-frag: B[k][col=(e,s)]; k 16..25 -> Win[e][s][k-16], k 26 -> b_in
            const int nt = idx >> 9, rem = idx & 511, lane = rem >> 3, j = rem & 7;
            const int k = ((lane >> 4) << 3) + j, col = nt*16 + (lane & 15);
            if (col < 30) {
                const int e = col / 10, s = col - e*10;
                if (k >= 16 && k < 26) val = RD(winv, e*100 + s*10 + (k-16));
                else if (k == 26)      val = RD(binv, e*10 + s);
            }
        } else if (idx < OFH) {
            // P3 A-frags Wr/Wz: A[row=s][k]; k<10 -> W[s][k], 16..25 -> W[s][10+..], 26 -> bias
            const int i2 = idx - OFR;
            const int mt = i2 >> 9, rem = i2 & 511, lane = rem >> 3, j = rem & 7;
            const int k = ((lane >> 4) << 3) + j, s = lane & 15;
            if (s < 10) {
                const void* Wv = mt ? wzv : wrv;
                const void* bv = mt ? bzv : brv;
                if (k < 10)                 val = RD(Wv, s*20 + k);
                else if (k >= 16 && k < 26) val = RD(Wv, s*20 + 10 + (k-16));
                else if (k == 26)           val = RD(bv, s);
            }
        } else if (idx < OFA) {
            const int i2 = idx - OFH;
            const int lane = i2 >> 3, j = i2 & 7;
            const int k = ((lane >> 4) << 3) + j, s = lane & 15;
            if (s < 10) {
                if (k < 10)                 val = RD(whv, s*20 + k);
                else if (k >= 16 && k < 26) val = RD(whv, s*20 + 10 + (k-16));
                else if (k == 26)           val = RD(bhv, s);
            }
        } else {
            // adjacency A-frag: A[m=node][k=e*72+mm]; zero at pads
            const int i2 = idx - OFA;
            const int w = i2 / 3584, rem = i2 - w*3584;
            const int kt = rem >> 9, r2 = rem & 511, lane = r2 >> 3, j = r2 & 7;
            const int m = w*16 + (lane & 15);
            const int k = kt*32 + ((lane >> 4) << 3) + j;
            const int e = k / 72, mm = k - e*72;
            if (m < NN && e < 3 && mm < NN) val = RD(Av, m*210 + e*70 + mm);
        }
        g_wf[idx] = (_Float16)val;
    }
    #undef RD
}

template<typename T>
__device__ __forceinline__ void run_impl(const void* annv, void* outv,
                                         _Float16* __restrict__ smh)
{
    const T* ann_g = (const T*)annv;
    T* out_g       = (T*)outv;
    _Float16* Uall = smh;
    _Float16* cat  = smh + UHALV;
    const int tid  = threadIdx.x;
    const int blk  = blockIdx.x;
    const int w    = tid >> 6;
    const int lane = tid & 63;
    const int q    = lane >> 4;
    const int c    = lane & 15;
    const int node  = w*16 + c;
    const int node0 = w*16 + q*4;
    const float* __restrict__ gw = g_w;

    // ---- preload all fragments from global (coalesced, once per block)
    const v8h w1f0 = *(const v8h*)&g_wf[       lane*8];
    const v8h w1f1 = *(const v8h*)&g_wf[512  + lane*8];
    const v8h wrf  = *(const v8h*)&g_wf[OFR  + lane*8];
    const v8h wzf  = *(const v8h*)&g_wf[OFZ  + lane*8];
    const v8h whf  = *(const v8h*)&g_wf[OFH  + lane*8];
    v8h a_adj[7];
    #pragma unroll
    for (int kt = 0; kt < 7; ++kt)
        a_adj[kt] = *(const v8h*)&g_wf[OFA + (w*7 + kt)*512 + lane*8];

    // ---- zero all dynamic LDS (phantom-node rows and pads MUST be zero)
    {
        const int4 zz = {0,0,0,0};
        int4* z = (int4*)smh;
        for (int idx = tid; idx < SMHALV/8; idx += TPB) z[idx] = zz;
    }
    __syncthreads();

    // ---- init: seed prop[0]=ann, bias-one at k=26 for all 6 graphs
    for (int idx = tid; idx < NB*NN; idx += TPB) {
        const int g = idx / NN, n2 = idx - g*NN;
        const int b2 = blk*NB + g;
        if (b2 < NTOT) {
            const float av = (float)ann_g[b2*NN + n2];
            const int bb = g / GPB, g2 = g - bb*GPB;
            cat[bb*CATB + g2*CATG + n2*CATN + 16] = (_Float16)av;
            cat[bb*CATB + g2*CATG + n2*CATN + 26] = (_Float16)1.0f;
        }
    }
    __syncthreads();

    // ---- P1: ins(prop) -> U[bb][par]
    #define PHASE1(BB,PAR) do {                                                  \
        _Float16* Ub_ = Uall + ((BB)*2+(PAR))*UBUF;                              \
        const _Float16* cb_ = cat + (BB)*CATB;                                   \
        _Pragma("unroll")                                                        \
        for (int g2 = 0; g2 < GPB; ++g2) {                                       \
            const v8h af = *(const v8h*)&cb_[g2*CATG + node*CATN + q*8];         \
            _Pragma("unroll")                                                    \
            for (int nt = 0; nt < 2; ++nt) {                                     \
                v4f acc = {0.f,0.f,0.f,0.f};                                     \
                acc = __builtin_amdgcn_mfma_f32_16x16x32_f16(                    \
                        af, nt ? w1f1 : w1f0, acc, 0,0,0);                       \
                const int colw = nt*16 + c;                                      \
                if (colw < 30 && node0 <= 68) {                                  \
                    const int e = colw / 10, s = colw - e*10;                    \
                    v4h hv = {(_Float16)acc[0],(_Float16)acc[1],                 \
                              (_Float16)acc[2],(_Float16)acc[3]};                \
                    *(v4h*)&Ub_[(g2*10 + s)*USTR + e*72 + node0] = hv;           \
                }                                                                \
            }                                                                    \
        }                                                                        \
    } while(0)

    // ---- P2: a_in = A_adj @ U[bb][par] -> cat k0..9
    #define PHASE2(BB,PAR) do {                                                  \
        const _Float16* Ub_ = Uall + ((BB)*2+(PAR))*UBUF;                        \
        _Float16* cb_ = cat + (BB)*CATB;                                         \
        _Pragma("unroll")                                                        \
        for (int nt = 0; nt < 2; ++nt) {                                         \
            v4f acc = {0.f,0.f,0.f,0.f};                                         \
            const _Float16* Up_ = &Ub_[(nt*16 + c)*USTR + q*8];                  \
            _Pragma("unroll")                                                    \
            for (int kt = 0; kt < 7; ++kt) {                                     \
                const v8h bf = *(const v8h*)(Up_ + kt*32);                       \
                acc = __builtin_amdgcn_mfma_f32_16x16x32_f16(a_adj[kt], bf, acc, 0,0,0); \
            }                                                                    \
            const int colc = nt*16 + c;                                          \
            if (colc < 30) {                                                     \
                const int g2 = colc / 10, s = colc - g2*10;                      \
                _Pragma("unroll")                                                \
                for (int r = 0; r < 4; ++r) {                                    \
                    const int nd = node0 + r;                                    \
                    if (nd < NN) cb_[g2*CATG + nd*CATN + s] = (_Float16)acc[r];  \
                }                                                                \
            }                                                                    \
        }                                                                        \
    } while(0)

    // ---- P3: gates (intra-wave: own nodes' cat rows)
    #define PHASE3(BB) do {                                                      \
        _Float16* cb_ = cat + (BB)*CATB;                                         \
        float zg[GPB][4], pg[GPB][4];                                            \
        _Pragma("unroll")                                                        \
        for (int g2 = 0; g2 < GPB; ++g2) {                                       \
            const v8h bf = *(const v8h*)&cb_[g2*CATG + node*CATN + q*8];         \
            v4f ar = {0.f,0.f,0.f,0.f}, az = {0.f,0.f,0.f,0.f};                  \
            ar = __builtin_amdgcn_mfma_f32_16x16x32_f16(wrf, bf, ar, 0,0,0);     \
            az = __builtin_amdgcn_mfma_f32_16x16x32_f16(wzf, bf, az, 0,0,0);     \
            const v4h pv = *(const v4h*)&cb_[g2*CATG + node*CATN + 16 + q*4];    \
            _Float16 rp[4];                                                      \
            _Pragma("unroll")                                                    \
            for (int i = 0; i < 4; ++i) {                                        \
                const float p = (float)pv[i];                                    \
                pg[g2][i] = p;                                                   \
                zg[g2][i] = fast_sigmoid(az[i]);                                 \
                rp[i] = (_Float16)(fast_sigmoid(ar[i]) * p);                     \
            }                                                                    \
            if (node < NN) {                                                     \
                _Float16* wp_ = &cb_[g2*CATG + node*CATN + 16 + q*4];            \
                if (q < 2)       *(v4h*)wp_ = (v4h){rp[0],rp[1],rp[2],rp[3]};    \
                else if (q == 2) *(v2h*)wp_ = (v2h){rp[0],rp[1]};                \
            }                                                                    \
        }                                                                        \
        _Pragma("unroll")                                                        \
        for (int g2 = 0; g2 < GPB; ++g2) {                                       \
            const v8h bf = *(const v8h*)&cb_[g2*CATG + node*CATN + q*8];         \
            v4f ah = {0.f,0.f,0.f,0.f};                                          \
            ah = __builtin_amdgcn_mfma_f32_16x16x32_f16(whf, bf, ah, 0,0,0);     \
            _Float16 pn[4];                                                      \
            _Pragma("unroll")                                                    \
            for (int i = 0; i < 4; ++i) {                                        \
                const float hh = fast_tanh(ah[i]);                               \
                pn[i] = (_Float16)(pg[g2][i] + zg[g2][i]*(hh - pg[g2][i]));      \
            }                                                                    \
            if (node < NN) {                                                     \
                _Float16* wp_ = &cb_[g2*CATG + node*CATN + 16 + q*4];            \
                if (q < 2)       *(v4h*)wp_ = (v4h){pn[0],pn[1],pn[2],pn[3]};    \
                else if (q == 2) *(v2h*)wp_ = (v2h){pn[0],pn[1]};                \
            }                                                                    \
        }                                                                        \
    } while(0)

    PHASE1(0,0);
    PHASE1(1,0);
    #pragma unroll 1
    for (int step = 0; step < STEPS; ++step) {
        const int par = step & 1;
        __syncthreads();   // U[*][par] complete; prior readers of U[*][par^1] done
        PHASE2(0,par); PHASE3(0); if (step < STEPS-1) PHASE1(0, par^1);
        PHASE2(1,par); PHASE3(1); if (step < STEPS-1) PHASE1(1, par^1);
    }
    #undef PHASE1
    #undef PHASE2
    #undef PHASE3
    __syncthreads();   // final prop visible for cross-wave epilogue mapping

    // ---- epilogue
    for (int idx = tid; idx < NB*NN; idx += TPB) {
        const int g = idx / NN, n2 = idx - g*NN;
        const int b2 = blk*NB + g;
        if (b2 >= NTOT) continue;
        const int bb = g / GPB, g2 = g - bb*GPB;
        const _Float16* pc = &cat[bb*CATB + g2*CATG + n2*CATN + 16];
        const v8h p8 = *(const v8h*)pc;
        const v2h p2 = *(const v2h*)(pc + 8);
        float pr[10];
        #pragma unroll
        for (int i = 0; i < 8; ++i) pr[i] = (float)p8[i];
        pr[8] = (float)p2[0]; pr[9] = (float)p2[1];
        const float av = (float)ann_g[b2*NN + n2];
        float o = gw[PBO2];
        #pragma unroll
        for (int s = 0; s < 10; ++s) {
            const float* wr_ = &gw[PWO1 + s*12];
            float acc = wr_[11] + wr_[10]*av;
            #pragma unroll
            for (int d = 0; d < 10; ++d) acc += pr[d]*wr_[d];
            o += fast_tanh(acc) * gw[PWO2 + s];
        }
        out_g[b2*NN + n2] = (T)o;
    }
}

// min-waves=2 -> 256-VGPR cap: LDS (94 KB) already forces 1 block/CU, so give
// the register allocator full room for the 2-batch interleaved streams.
__global__ __launch_bounds__(TPB, 2)
void ggnn_kernel(const void* annv, void* outv)
{
    extern __shared__ _Float16 smh[];
    if (g_flag)
        run_impl<__hip_bfloat16>(annv, outv, smh);
    else
        run_impl<float>(annv, outv, smh);
}

extern "C" void kernel_launch(void* const* d_in, const int* in_sizes, int n_in,
                              void* d_out, int out_size, void* d_ws, size_t ws_size,
                              hipStream_t stream) {
    (void)in_sizes; (void)n_in; (void)out_size; (void)d_ws; (void)ws_size;
    // opt-in to >64KB dynamic LDS (host-side attribute, idempotent, not
    // stream-ordered -> graph-capture-safe). R11 proved this path executes.
    hipFuncSetAttribute(reinterpret_cast<const void*>(ggnn_kernel),
                        hipFuncAttributeMaxDynamicSharedMemorySize, SMBYTES);
    hipLaunchKernelGGL(prep_kernel, dim3(1), dim3(256), 0, stream,
        d_in[0], d_in[1], d_in[2], d_in[3], d_in[4], d_in[5], d_in[6],
        d_in[7], d_in[8], d_in[9], d_in[10], d_in[11], d_in[12], d_in[13]);
    hipLaunchKernelGGL(ggnn_kernel, dim3(NBLK), dim3(TPB), SMBYTES, stream,
        d_in[0], d_out);
}

// Round 13
// 298.051 us; speedup vs baseline: 1.4034x; 1.4034x over previous
//
#include <hip/hip_runtime.h>
#include <hip/hip_bf16.h>

typedef _Float16 v8h __attribute__((ext_vector_type(8)));
typedef _Float16 v4h __attribute__((ext_vector_type(4)));
typedef _Float16 v2h __attribute__((ext_vector_type(2)));
typedef float    v4f __attribute__((ext_vector_type(4)));

#define NTOT  16384
#define NN    70
#define STEPS 5
#define TPB   64                     // ONE wave per block; one graph per block
#define NBLK  NTOT                   // 16384 blocks
#define CATN  40                     // cat node stride (halves)
#define CATH  3208                   // cat total halves (80 nodes * 40 + pad)
#define USTR  232                    // U col stride (halves): 116 dw == 20 mod 32
#define UH    (16*USTR)              // 3712 halves (cols 10..15 phantom-zero)

// epilogue weights (fp32, global scalar loads)
#define PWO1 0                       // 10 rows x 12: [Wo1[s][0..9], ann_coef, bo1[s]]
#define PWO2 120
#define PBO2 130
#define NWP  132

// fp16 fragment images (built by prep):
//  [0..1023]     P1 B-frags Wstack, 2 tiles:  nt*512 + lane*8 + j
//  [1024..2047]  P3 A-frags Wr | Wz:          mt*512 + lane*8 + j
//  [2048..2559]  P3 A-frag  Wh:               lane*8 + j
//  [2560..20479] adjacency A-frags:           2560 + (mt*7+kt)*512 + lane*8 + j
#define OFR  1024
#define OFZ  1536
#define OFH  2048
#define OFA  2560
#define NWF  20480

__device__ __align__(16) float    g_w[NWP];
__device__ __align__(16) _Float16 g_wf[NWF];
__device__ int g_flag;

__device__ __forceinline__ float fast_sigmoid(float x) {
    return __builtin_amdgcn_rcpf(1.0f + __expf(-x));
}
__device__ __forceinline__ float fast_tanh(float x) {
    float ax = fabsf(x);
    float e  = __expf(-2.0f * ax);
    float t  = (1.0f - e) * __builtin_amdgcn_rcpf(1.0f + e);
    return copysignf(t, x);
}

struct __align__(16) Smem {
    _Float16 U[UH];      // 7424 B: U[col=s][k=e*72+node]
    _Float16 cat[CATH];  // 6416 B: cat[node][k]; k0..9=a_in, 16..25=prop, 26=1
};
// 13840 B/block; residency bound by VGPRs (~2 waves/SIMD = 8 blocks/CU)

// ---- prep: probe dtype; build epilogue weights + all fp16 fragment images ----
__global__ void prep_kernel(const void* annv, const void* Av,
    const void* winv, const void* binv, const void* wrv, const void* brv,
    const void* wzv, const void* bzv, const void* whv, const void* bhv,
    const void* wo1v, const void* bo1v, const void* wo2v, const void* bo2v)
{
    __shared__ int sflag;
    if (threadIdx.x == 0) {
        const unsigned short* u = (const unsigned short*)annv;
        int good = 0;
        for (int k = 0; k < 128; ++k) {
            unsigned short bb = u[k];
            int ex = (bb >> 7) & 0xFF;
            if (bb == 0 || (ex >= 101 && ex <= 131)) ++good;
        }
        sflag = (good >= 112) ? 1 : 0;
        g_flag = sflag;
    }
    __syncthreads();
    const int f = sflag;
    #define RD(p, i) (f ? (float)((const __hip_bfloat16*)(p))[i] : ((const float*)(p))[i])
    const int tid = threadIdx.x;
    for (int idx = tid; idx < 120; idx += blockDim.x) {
        const int s = idx / 12, c = idx - s*12;
        g_w[PWO1 + idx] = (c < 11) ? RD(wo1v, s*11 + c) : RD(bo1v, s);
    }
    for (int idx = tid; idx < 10; idx += blockDim.x) g_w[PWO2 + idx] = RD(wo2v, idx);
    if (tid == 0) { g_w[PBO2] = RD(bo2v, 0); g_w[PBO2+1] = 0.f; }
    for (int idx = tid; idx < NWF; idx += blockDim.x) {
        float val = 0.f;
        if (idx < OFR) {
            // P1 B-frag: B[k][col=(e,s)]; k 16..25 -> Win[e][s][k-16], k 26 -> b_in
            const int nt = idx >> 9, rem = idx & 511, lane = rem >> 3, j = rem & 7;
            const int k = ((lane >> 4) << 3) + j, col = nt*16 + (lane & 15);
            if (col < 30) {
                const int e = col / 10, s = col - e*10;
                if (k >= 16 && k < 26) val = RD(winv, e*100 + s*10 + (k-16));
                else if (k == 26)      val = RD(binv, e*10 + s);
            }
        } else if (idx < OFH) {
            // P3 A-frags Wr/Wz: A[row=s][k]; k<10 -> W[s][k], 16..25 -> W[s][10+..], 26 -> bias
            const int i2 = idx - OFR;
            const int mt = i2 >> 9, rem = i2 & 511, lane = rem >> 3, j = rem & 7;
            const int k = ((lane >> 4) << 3) + j, s = lane & 15;
            if (s < 10) {
                const void* Wv = mt ? wzv : wrv;
                const void* bv = mt ? bzv : brv;
                if (k < 10)                 val = RD(Wv, s*20 + k);
                else if (k >= 16 && k < 26) val = RD(Wv, s*20 + 10 + (k-16));
                else if (k == 26)           val = RD(bv, s);
            }
        } else if (idx < OFA) {
            const int i2 = idx - OFH;
            const int lane = i2 >> 3, j = i2 & 7;
            const int k = ((lane >> 4) << 3) + j, s = lane & 15;
            if (s < 10) {
                if (k < 10)                 val = RD(whv, s*20 + k);
                else if (k >= 16 && k < 26) val = RD(whv, s*20 + 10 + (k-16));
                else if (k == 26)           val = RD(bhv, s);
            }
        } else {
            // adjacency A-frag: A[m=node][k=e*72+mm]; zero at pads
            const int i2 = idx - OFA;
            const int w = i2 / 3584, rem = i2 - w*3584;
            const int kt = rem >> 9, r2 = rem & 511, lane = r2 >> 3, j = r2 & 7;
            const int m = w*16 + (lane & 15);
            const int k = kt*32 + ((lane >> 4) << 3) + j;
            const int e = k / 72, mm = k - e*72;
            if (m < NN && e < 3 && mm < NN) val = RD(Av, m*210 + e*70 + mm);
        }
        g_wf[idx] = (_Float16)val;
    }
    #undef RD
}

template<typename T>
__device__ __forceinline__ void run_impl(const void* annv, void* outv, Smem& sm)
{
    const T* ann_g = (const T*)annv;
    T* out_g       = (T*)outv;
    const int lane = threadIdx.x;    // single wave
    const int blk  = blockIdx.x;     // == graph id
    const int q    = lane >> 4;
    const int c    = lane & 15;
    const float* __restrict__ gw = g_w;

    // ---- preload ALL fragments into registers (once per block)
    const v8h w1f0 = *(const v8h*)&g_wf[       lane*8];
    const v8h w1f1 = *(const v8h*)&g_wf[512  + lane*8];
    const v8h wrf  = *(const v8h*)&g_wf[OFR  + lane*8];
    const v8h wzf  = *(const v8h*)&g_wf[OFZ  + lane*8];
    const v8h whf  = *(const v8h*)&g_wf[OFH  + lane*8];
    v8h adj[35];   // 140 VGPRs: all 5 M-tiles x 7 K-tiles of adjacency
    #pragma unroll
    for (int i = 0; i < 35; ++i)
        adj[i] = *(const v8h*)&g_wf[OFA + i*512 + lane*8];

    // ---- zero LDS (phantom rows/cols MUST be zero)
    {
        const int4 zz = {0,0,0,0};
        int4* z = (int4*)&sm;
        #pragma unroll 4
        for (int i = lane; i < (int)(sizeof(Smem)/16); i += TPB) z[i] = zz;
    }
    __syncthreads();

    // ---- seed: prop[0]=ann at k=16, bias-one at k=26
    for (int n2 = lane; n2 < NN; n2 += TPB) {
        sm.cat[n2*CATN + 16] = (_Float16)(float)ann_g[blk*NN + n2];
        sm.cat[n2*CATN + 26] = (_Float16)1.0f;
    }
    __syncthreads();

    // ---- P1: ins(prop) -> U   (A=cat rows, B=Wstack frags)
    #define PHASE1() do {                                                        \
        _Pragma("unroll")                                                        \
        for (int mt = 0; mt < 5; ++mt) {                                         \
            const v8h af = *(const v8h*)&sm.cat[(mt*16 + c)*CATN + q*8];         \
            const int node0 = mt*16 + q*4;                                       \
            _Pragma("unroll")                                                    \
            for (int nt = 0; nt < 2; ++nt) {                                     \
                v4f acc = {0.f,0.f,0.f,0.f};                                     \
                acc = __builtin_amdgcn_mfma_f32_16x16x32_f16(                    \
                        af, nt ? w1f1 : w1f0, acc, 0,0,0);                       \
                const int colw = nt*16 + c;                                      \
                if (colw < 30 && node0 <= 68) {                                  \
                    const int e = colw / 10, s = colw - e*10;                    \
                    v4h hv = {(_Float16)acc[0],(_Float16)acc[1],                 \
                              (_Float16)acc[2],(_Float16)acc[3]};                \
                    *(v4h*)&sm.U[s*USTR + e*72 + node0] = hv;                    \
                }                                                                \
            }                                                                    \
        }                                                                        \
    } while(0)

    PHASE1();
    __syncthreads();

    #pragma unroll 1
    for (int step = 0; step < STEPS; ++step) {
        // ---- P2: a_in = A_adj @ U  (B-frags read ONCE, reused across 5 M-tiles)
        {
            v8h bfr[7];
            #pragma unroll
            for (int kt = 0; kt < 7; ++kt)
                bfr[kt] = *(const v8h*)&sm.U[c*USTR + q*8 + kt*32];
            #pragma unroll
            for (int mt = 0; mt < 5; ++mt) {
                v4f acc = {0.f,0.f,0.f,0.f};
                #pragma unroll
                for (int kt = 0; kt < 7; ++kt)
                    acc = __builtin_amdgcn_mfma_f32_16x16x32_f16(adj[mt*7+kt], bfr[kt], acc, 0,0,0);
                const int node0 = mt*16 + q*4;
                if (c < 10) {
                    #pragma unroll
                    for (int r = 0; r < 4; ++r) {
                        const int nd = node0 + r;
                        if (nd < NN) sm.cat[nd*CATN + c] = (_Float16)acc[r];
                    }
                }
            }
        }
        __syncthreads();   // a_in visible to all lanes

        // ---- P3: gates per N-tile (r,z -> rp write -> fence -> h -> pn write)
        #pragma unroll
        for (int nt = 0; nt < 5; ++nt) {
            const int node = nt*16 + c;
            const v8h bf = *(const v8h*)&sm.cat[node*CATN + q*8];
            v4f ar = {0.f,0.f,0.f,0.f}, az = {0.f,0.f,0.f,0.f};
            ar = __builtin_amdgcn_mfma_f32_16x16x32_f16(wrf, bf, ar, 0,0,0);
            az = __builtin_amdgcn_mfma_f32_16x16x32_f16(wzf, bf, az, 0,0,0);
            const v4h pv = *(const v4h*)&sm.cat[node*CATN + 16 + q*4];
            float zg[4], pg[4];
            _Float16 rp[4];
            #pragma unroll
            for (int i = 0; i < 4; ++i) {
                const float p = (float)pv[i];
                pg[i] = p;
                zg[i] = fast_sigmoid(az[i]);
                rp[i] = (_Float16)(fast_sigmoid(ar[i]) * p);
            }
            if (node < NN) {
                _Float16* wp = &sm.cat[node*CATN + 16 + q*4];
                if (q < 2)       *(v4h*)wp = (v4h){rp[0],rp[1],rp[2],rp[3]};
                else if (q == 2) *(v2h*)wp = (v2h){rp[0],rp[1]};
            }
            __syncthreads();   // rp visible cross-lane (1-wave barrier: cheap fence)
            const v8h bf2 = *(const v8h*)&sm.cat[node*CATN + q*8];
            v4f ah = {0.f,0.f,0.f,0.f};
            ah = __builtin_amdgcn_mfma_f32_16x16x32_f16(whf, bf2, ah, 0,0,0);
            _Float16 pn[4];
            #pragma unroll
            for (int i = 0; i < 4; ++i) {
                const float hh = fast_tanh(ah[i]);
                pn[i] = (_Float16)(pg[i] + zg[i]*(hh - pg[i]));
            }
            if (node < NN) {
                _Float16* wp = &sm.cat[node*CATN + 16 + q*4];
                if (q < 2)       *(v4h*)wp = (v4h){pn[0],pn[1],pn[2],pn[3]};
                else if (q == 2) *(v2h*)wp = (v2h){pn[0],pn[1]};
            }
        }
        __syncthreads();   // new prop visible

        // ---- P1 for next step
        if (step < STEPS-1) {
            PHASE1();
            __syncthreads();
        }
    }
    #undef PHASE1

    // ---- epilogue: one output per node
    for (int n2 = lane; n2 < NN; n2 += TPB) {
        const _Float16* pc = &sm.cat[n2*CATN + 16];
        const v8h p8 = *(const v8h*)pc;
        const v2h p2 = *(const v2h*)(pc + 8);
        float pr[10];
        #pragma unroll
        for (int i = 0; i < 8; ++i) pr[i] = (float)p8[i];
        pr[8] = (float)p2[0]; pr[9] = (float)p2[1];
        const float av = (float)ann_g[blk*NN + n2];
        float o = gw[PBO2];
        #pragma unroll
        for (int s = 0; s < 10; ++s) {
            const float* wr_ = &gw[PWO1 + s*12];
            float acc = wr_[11] + wr_[10]*av;
            #pragma unroll
            for (int d = 0; d < 10; ++d) acc += pr[d]*wr_[d];
            o += fast_tanh(acc) * gw[PWO2 + s];
        }
        out_g[blk*NN + n2] = (T)o;
    }
}

// min-waves=2 -> 256-VGPR cap. Live set ~220 (adj 140 + weights 28 + temps);
// MUST NOT spill (tripwire: WRITE_SIZE). 2 waves/SIMD = 8 independent
// graph-pipelines per CU, zero cross-wave barrier coupling.
__global__ __launch_bounds__(TPB, 2)
void ggnn_kernel(const void* annv, void* outv)
{
    __shared__ Smem sm;
    if (g_flag)
        run_impl<__hip_bfloat16>(annv, outv, sm);
    else
        run_impl<float>(annv, outv, sm);
}

extern "C" void kernel_launch(void* const* d_in, const int* in_sizes, int n_in,
                              void* d_out, int out_size, void* d_ws, size_t ws_size,
                              hipStream_t stream) {
    (void)in_sizes; (void)n_in; (void)out_size; (void)d_ws; (void)ws_size;
    hipLaunchKernelGGL(prep_kernel, dim3(1), dim3(256), 0, stream,
        d_in[0], d_in[1], d_in[2], d_in[3], d_in[4], d_in[5], d_in[6],
        d_in[7], d_in[8], d_in[9], d_in[10], d_in[11], d_in[12], d_in[13]);
    hipLaunchKernelGGL(ggnn_kernel, dim3(NBLK), dim3(TPB), 0, stream,
        d_in[0], d_out);
}